// Round 10
// baseline (926.627 us; speedup 1.0000x reference)
//
#include <hip/hip_runtime.h>

#define NTOK  384
#define SPANS 73920          // 384*385/2
#define MTILES 584           // 73*8 so grid=584*8 maps cleanly onto 8 XCDs
#define MPAD  (MTILES * 128) // 74752
#define HD    1024
#define BK    32
#define KTS   (HD / BK)      // 32

typedef unsigned short u16;
typedef __attribute__((ext_vector_type(8))) short short8;
typedef __attribute__((ext_vector_type(4))) float floatx4;

// gfx9 s_waitcnt immediate: vmcnt[3:0]|[15:14], expcnt[6:4], lgkmcnt[11:8]
#define VMCNT_IMM(N) (((N) & 0xF) | (((N) >> 4) << 14) | (0x7 << 4) | (0xF << 8))

__device__ __forceinline__ u16 f2bu(float x) {
  union { float f; unsigned u; } un; un.f = x;
  unsigned r = un.u + 0x7fffu + ((un.u >> 16) & 1u);   // RNE
  return (u16)(r >> 16);
}

__device__ __forceinline__ void gld_lds16(const void* g, void* l) {
  __builtin_amdgcn_global_load_lds(
      (const __attribute__((address_space(1))) void*)g,
      (__attribute__((address_space(3))) void*)l, 16, 0, 0);
}

// ---- prep: prefix sums via per-column parallel scan (block = one column) ----
__global__ void prep_pref(const int* __restrict__ sent, const int* __restrict__ pos,
                          const float* __restrict__ Wwrd, const float* __restrict__ Wpos,
                          float* __restrict__ pref) {
  __shared__ float buf[NTOK];
  int c = blockIdx.x;           // 0..1023
  int t = threadIdx.x;          // 0..383
  float v = (c < 512) ? Wpos[(size_t)pos[t] * 512 + c]
                      : Wwrd[(size_t)sent[t] * 512 + (c - 512)];
  buf[t] = v;
  __syncthreads();
  #pragma unroll
  for (int off = 1; off < NTOK; off <<= 1) {
    float add = (t >= off) ? buf[t - off] : 0.f;
    __syncthreads();
    buf[t] += add;
    __syncthreads();
  }
  if (t == 0) pref[c] = 0.f;
  pref[(size_t)(t + 1) * HD + c] = buf[t];
}

// ---- prep: span (i, end, 1/len) + scores init (folded) ----
__global__ void prep_spans(int* __restrict__ spI, int* __restrict__ spE, float* __restrict__ spInv,
                           float* __restrict__ scores, const float* __restrict__ bs2) {
  int rf = blockIdx.x * 256 + threadIdx.x;
  if (rf >= MPAD) return;
  int s = rf < SPANS ? rf : SPANS - 1;
  const int n = NTOK;
  double tn = 2.0 * n + 1.0;
  int i = (int)((tn - sqrt(tn * tn - 8.0 * (double)s)) * 0.5);
  if (i < 0) i = 0;
  if (i > n - 1) i = n - 1;
  #define OFF(ii) (((ii) * (2 * n - (ii) + 1)) / 2)
  while (i + 1 <= n - 1 && OFF(i + 1) <= s) ++i;
  while (i > 0 && OFF(i) > s) --i;
  int j = i + (s - OFF(i));
  #undef OFF
  spI[rf] = i;
  spE[rf] = j + 1;
  spInv[rf] = 1.0f / (float)(j + 1 - i);
  if (rf < SPANS) scores[rf] = bs2[0];
}

// ---- prep: transpose+cast the three 1024x1024 weight blocks to bf16 B^T [N][K] ----
__global__ void prep_castT(const float* __restrict__ Wd1, const float* __restrict__ Wd2,
                           const float* __restrict__ Ws1,
                           u16* __restrict__ o1, u16* __restrict__ o2, u16* __restrict__ o3) {
  int b = blockIdx.x;           // 3*1024 blocks
  int w = b >> 10, rem = b & 1023;
  int tk = rem >> 5, tn = rem & 31;
  const float* src = (w == 0) ? Wd1 : ((w == 1) ? Wd2 : Ws1);
  u16* dst = (w == 0) ? o1 : ((w == 1) ? o2 : o3);
  __shared__ u16 tile[32][33];
  int x = threadIdx.x & 31, y = threadIdx.x >> 5;   // y in 0..7
  int k0 = tk * 32, n0 = tn * 32;
  for (int yy = 0; yy < 32; yy += 8)
    tile[y + yy][x] = f2bu(src[(size_t)(k0 + y + yy) * HD + n0 + x]);
  __syncthreads();
  for (int yy = 0; yy < 32; yy += 8)
    dst[(size_t)(n0 + y + yy) * HD + k0 + x] = tile[x][y + yy];
}

// ---- prep: S0/S1/S2 = column sums of W_s1's feat rows (len/start/end, 16 each), exact fp32 ----
__global__ void prep_svec(const float* __restrict__ Ws1,
                          float* __restrict__ S0, float* __restrict__ S1v, float* __restrict__ S2v) {
  int c = blockIdx.x * 256 + threadIdx.x;
  if (c >= HD) return;
  float a = 0.f, b = 0.f, d = 0.f;
  for (int r = 0; r < 16; ++r) {
    a += Ws1[(size_t)(1024 + r) * HD + c];
    b += Ws1[(size_t)(1040 + r) * HD + c];
    d += Ws1[(size_t)(1056 + r) * HD + c];
  }
  S0[c] = a; S1v[c] = b; S2v[c] = d;
}

// ---- prep: span means -> bf16 [MPAD][1024] ----
__global__ void prep_mean(const float* __restrict__ pref, const int* __restrict__ spI,
                          const int* __restrict__ spE, const float* __restrict__ spInv,
                          u16* __restrict__ out) {
  int gid = blockIdx.x * 256 + threadIdx.x;   // MPAD*128 threads
  int row = gid >> 7;
  int c0 = (gid & 127) << 3;
  int i = spI[row], e = spE[row];
  float inv = spInv[row];
  const float* pe = pref + (size_t)e * HD + c0;
  const float* pi = pref + (size_t)i * HD + c0;
  u16 tmp[8];
  #pragma unroll
  for (int u = 0; u < 8; ++u) tmp[u] = f2bu((pe[u] - pi[u]) * inv);
  *(uint4*)(out + (size_t)row * HD + c0) = *(const uint4*)tmp;
}

// ---- GEMM: C[M,1024] = relu(A[M,1024] @ B^T[1024,1024]^T + bias)
// R7 geometry (128x128 tile, 4 waves of 64x64, 16x16x32 MFMA, BK=32,
// 0-conflict stripe layout) with a restructured pipeline: FOUR LDS buffer
// slots (64 KB), prefetch depth 2, ONE barrier per kt. stage(kt+2) overwrites
// the buffer last read at kt-2; the collective barrier at kt-1 already
// guarantees all waves are past those reads, so the trailing barrier of the
// classic ping-pong is provably unnecessary. vmcnt(8) keeps 2 stages in
// flight -> each DMA op gets ~2 compute windows to complete (R6-R9 gave 1,
// exposing L2/HBM staging latency every kt — the 220 us invariant).
// EPI==0: store bf16 C.  EPI==1: + feats affine, relu, dot W_s2, atomicAdd scores.
template <int EPI>
__global__ __launch_bounds__(256, 2) void gemm_bt(
    const u16* __restrict__ A, const u16* __restrict__ Bt,
    const float* __restrict__ bias, u16* __restrict__ C,
    const int* __restrict__ spI, const int* __restrict__ spE,
    const float* __restrict__ S0, const float* __restrict__ S1v, const float* __restrict__ S2v,
    const float* __restrict__ Ws2, float* __restrict__ scores) {
  __shared__ u16 As[4][128 * BK];   // 4 slots x 8 KB
  __shared__ u16 Bs[4][128 * BK];
  int bx = blockIdx.x;
  int xcd = bx & 7, k = bx >> 3;
  int nt = k & 7;
  int mt = xcd + 8 * (k >> 3);     // mt%8 == xcd; consecutive blocks per XCD share mt (A L2 reuse)
  int m0 = mt * 128, n0 = nt * 128;
  int t = threadIdx.x, lane = t & 63, wid = t >> 6;
  int wm = wid >> 1, wn = wid & 1;
  int q = lane >> 4, r = lane & 15;

  floatx4 acc[4][4] = {};

  // ---- staging geometry (stripe s holds rows 2s,2s+1; sub=(row&1)*4+koct at
  // octet sub^(s&7); one DMA op = 16 rows x 64B, swizzle invariant under +64 rows) ----
  int dsub = (lane & 7) ^ ((lane >> 3) & 7);
  int row0 = wid * 16 + 2 * (lane >> 3) + (dsub >> 2);
  int voff = row0 * HD + (dsub & 3) * 8;          // u16 elems; kt-invariant
  const u16* gA0 = A  + (size_t)m0 * HD;
  const u16* gB0 = Bt + (size_t)n0 * HD;
  int ldsOff0 = wid * 512;                        // u16; wave-uniform dests
  int ldsOff1 = 2048 + wid * 512;                 // +64 rows = +32 stripes

  auto stage = [&](int kt, int b) {
    const u16* pa = gA0 + voff + kt * BK;
    const u16* pb = gB0 + voff + kt * BK;
    gld_lds16(pa,                   &As[b][ldsOff0]);
    gld_lds16(pa + (size_t)64 * HD, &As[b][ldsOff1]);
    gld_lds16(pb,                   &Bs[b][ldsOff0]);
    gld_lds16(pb + (size_t)64 * HD, &Bs[b][ldsOff1]);
  };

  // ---- fragment read offsets (u16 elements) ----
  // row = w*64 + x*16 + r, stripe s = row>>1, oct = ((row&1)*4 + q) ^ (s&7)
  int oct = (((r & 1) << 2) + q) ^ ((r >> 1) & 7);
  int aoff[4], boff[4];
  #pragma unroll
  for (int x = 0; x < 4; ++x) {
    aoff[x] = (wm * 32 + x * 8 + (r >> 1)) * 64 + oct * 8;
    boff[x] = (wn * 32 + x * 8 + (r >> 1)) * 64 + oct * 8;
  }

  auto compute = [&](int b) {
    short8 af[4];
    #pragma unroll
    for (int x = 0; x < 4; ++x) af[x] = *(const short8*)(&As[b][aoff[x]]);
    #pragma unroll
    for (int ni = 0; ni < 4; ++ni) {
      short8 bf = *(const short8*)(&Bs[b][boff[ni]]);
      #pragma unroll
      for (int mi = 0; mi < 4; ++mi)
        acc[mi][ni] = __builtin_amdgcn_mfma_f32_16x16x32_bf16(af[mi], bf, acc[mi][ni], 0, 0, 0);
    }
  };

  stage(0, 0);
  stage(1, 1);
  #pragma unroll 1
  for (int kt = 0; kt < KTS; ++kt) {
    if (kt < KTS - 2) {
      stage(kt + 2, (kt + 2) & 3);
      __builtin_amdgcn_s_waitcnt(VMCNT_IMM(8));   // kt's 4 done; kt+1, kt+2 in flight
    } else if (kt == KTS - 2) {
      __builtin_amdgcn_s_waitcnt(VMCNT_IMM(4));   // kt's 4 done; kt+1 in flight
    } else {
      __builtin_amdgcn_s_waitcnt(VMCNT_IMM(0));
    }
    __builtin_amdgcn_s_barrier();                 // single barrier per kt
    compute(kt & 3);
  }

  if (EPI == 0) {
    #pragma unroll
    for (int mi = 0; mi < 4; ++mi) {
      int rowb = m0 + wm * 64 + mi * 16 + q * 4;
      #pragma unroll
      for (int ni = 0; ni < 4; ++ni) {
        int col = n0 + wn * 64 + ni * 16 + r;
        float bcol = bias[col];
        #pragma unroll
        for (int e = 0; e < 4; ++e) {
          float v = acc[mi][ni][e] + bcol;
          v = v > 0.f ? v : 0.f;
          C[(size_t)(rowb + e) * HD + col] = f2bu(v);
        }
      }
    }
  } else {
    float bcol[4], s0c[4], s1c[4], s2c[4], wsc[4];
    #pragma unroll
    for (int ni = 0; ni < 4; ++ni) {
      int col = n0 + wn * 64 + ni * 16 + r;
      bcol[ni] = bias[col]; s0c[ni] = S0[col]; s1c[ni] = S1v[col];
      s2c[ni] = S2v[col];  wsc[ni] = Ws2[col];
    }
    #pragma unroll
    for (int mi = 0; mi < 4; ++mi) {
      int rowb = m0 + wm * 64 + mi * 16 + q * 4;
      #pragma unroll
      for (int e = 0; e < 4; ++e) {
        int row = rowb + e;
        float fi = (float)spI[row];
        float fe = (float)spE[row];
        float fl = fe - fi;
        float p = 0.f;
        #pragma unroll
        for (int ni = 0; ni < 4; ++ni) {
          float v = acc[mi][ni][e] + bcol[ni] + fl * s0c[ni] + fi * s1c[ni] + fe * s2c[ni];
          v = v > 0.f ? v : 0.f;
          p += v * wsc[ni];
        }
        p += __shfl_xor(p, 1);
        p += __shfl_xor(p, 2);
        p += __shfl_xor(p, 4);
        p += __shfl_xor(p, 8);
        if (r == 0 && row < SPANS) atomicAdd(&scores[row], p);
      }
    }
  }
}

extern "C" void kernel_launch(void* const* d_in, const int* in_sizes, int n_in,
                              void* d_out, int out_size, void* d_ws, size_t ws_size,
                              hipStream_t stream) {
  const int*   sent = (const int*)d_in[0];
  const int*   pos  = (const int*)d_in[1];
  const float* Wwrd = (const float*)d_in[2];
  const float* Wpos = (const float*)d_in[3];
  const float* Wd1  = (const float*)d_in[4];
  const float* bd1  = (const float*)d_in[5];
  const float* Wd2  = (const float*)d_in[6];
  const float* bd2  = (const float*)d_in[7];
  const float* Ws1  = (const float*)d_in[8];
  const float* bs1  = (const float*)d_in[9];
  const float* Ws2  = (const float*)d_in[10];
  const float* bs2  = (const float*)d_in[11];
  float* scores = (float*)d_out;

  char* w = (char*)d_ws;
  size_t o = 0;
  auto alloc = [&](size_t bytes) {
    char* p = w + o;
    o = (o + bytes + 255) & ~(size_t)255;
    return p;
  };
  float* pref  = (float*)alloc((size_t)385 * HD * 4);
  int*   spI   = (int*)  alloc((size_t)MPAD * 4);
  int*   spE   = (int*)  alloc((size_t)MPAD * 4);
  float* spInv = (float*)alloc((size_t)MPAD * 4);
  float* S0    = (float*)alloc(4096);
  float* S1v   = (float*)alloc(4096);
  float* S2v   = (float*)alloc(4096);
  u16* Wd1t = (u16*)alloc((size_t)HD * HD * 2);
  u16* Wd2t = (u16*)alloc((size_t)HD * HD * 2);
  u16* Ws1t = (u16*)alloc((size_t)HD * HD * 2);
  u16* bufA = (u16*)alloc((size_t)MPAD * HD * 2);
  u16* bufB = (u16*)alloc((size_t)MPAD * HD * 2);

  prep_pref <<<HD, NTOK, 0, stream>>>(sent, pos, Wwrd, Wpos, pref);
  prep_spans<<<(MPAD + 255) / 256, 256, 0, stream>>>(spI, spE, spInv, scores, bs2);
  prep_castT<<<3 * 1024, 256, 0, stream>>>(Wd1, Wd2, Ws1, Wd1t, Wd2t, Ws1t);
  prep_svec <<<4, 256, 0, stream>>>(Ws1, S0, S1v, S2v);
  prep_mean <<<MPAD / 2, 256, 0, stream>>>(pref, spI, spE, spInv, bufA);

  gemm_bt<0><<<MTILES * 8, 256, 0, stream>>>(bufA, Wd1t, bd1, bufB,
                                             nullptr, nullptr, nullptr, nullptr, nullptr, nullptr, nullptr);
  gemm_bt<0><<<MTILES * 8, 256, 0, stream>>>(bufB, Wd2t, bd2, bufA,
                                             nullptr, nullptr, nullptr, nullptr, nullptr, nullptr, nullptr);
  gemm_bt<1><<<MTILES * 8, 256, 0, stream>>>(bufA, Ws1t, bs1, nullptr,
                                             spI, spE, S0, S1v, S2v, Ws2, scores);
}

// Round 11
// 595.214 us; speedup vs baseline: 1.5568x; 1.5568x over previous
//
#include <hip/hip_runtime.h>

#define NTOK  384
#define SPANS 73920          // 384*385/2
#define MTILES 584           // 73*8 so grid=584*8 maps cleanly onto 8 XCDs
#define MPAD  (MTILES * 128) // 74752
#define HD    1024
#define BK    32
#define KTS   (HD / BK)      // 32

typedef unsigned short u16;
typedef __attribute__((ext_vector_type(8))) short short8;
typedef __attribute__((ext_vector_type(4))) float floatx4;

// gfx9 s_waitcnt immediate: vmcnt[3:0]|[15:14], expcnt[6:4], lgkmcnt[11:8]
#define VMCNT_IMM(N) (((N) & 0xF) | (((N) >> 4) << 14) | (0x7 << 4) | (0xF << 8))

__device__ __forceinline__ u16 f2bu(float x) {
  union { float f; unsigned u; } un; un.f = x;
  unsigned r = un.u + 0x7fffu + ((un.u >> 16) & 1u);   // RNE
  return (u16)(r >> 16);
}

__device__ __forceinline__ void gld_lds16(const void* g, void* l) {
  __builtin_amdgcn_global_load_lds(
      (const __attribute__((address_space(1))) void*)g,
      (__attribute__((address_space(3))) void*)l, 16, 0, 0);
}

// ---- prep: gather token embeddings as bf16 [384][1024] (A of the Y-GEMM) ----
__global__ void emb_gather(const int* __restrict__ sent, const int* __restrict__ pos,
                           const float* __restrict__ Wwrd, const float* __restrict__ Wpos,
                           u16* __restrict__ embB) {
  int t = blockIdx.x;           // token
  int c = threadIdx.x;          // 0..255
  int pt = pos[t], st = sent[t];
  #pragma unroll
  for (int u = 0; u < 4; ++u) {
    int col = u * 256 + c;
    float v = (col < 512) ? Wpos[(size_t)pt * 512 + col]
                          : Wwrd[(size_t)st * 512 + (col - 512)];
    embB[(size_t)t * HD + col] = f2bu(v);
  }
}

// ---- prep: span (i, end, 1/len) + scores init (folded) ----
__global__ void prep_spans(int* __restrict__ spI, int* __restrict__ spE, float* __restrict__ spInv,
                           float* __restrict__ scores, const float* __restrict__ bs2) {
  int rf = blockIdx.x * 256 + threadIdx.x;
  if (rf >= MPAD) return;
  int s = rf < SPANS ? rf : SPANS - 1;
  const int n = NTOK;
  double tn = 2.0 * n + 1.0;
  int i = (int)((tn - sqrt(tn * tn - 8.0 * (double)s)) * 0.5);
  if (i < 0) i = 0;
  if (i > n - 1) i = n - 1;
  #define OFF(ii) (((ii) * (2 * n - (ii) + 1)) / 2)
  while (i + 1 <= n - 1 && OFF(i + 1) <= s) ++i;
  while (i > 0 && OFF(i) > s) --i;
  int j = i + (s - OFF(i));
  #undef OFF
  spI[rf] = i;
  spE[rf] = j + 1;
  spInv[rf] = 1.0f / (float)(j + 1 - i);
  if (rf < SPANS) scores[rf] = bs2[0];
}

// ---- prep: transpose+cast the three 1024x1024 weight blocks to bf16 B^T [N][K] ----
__global__ void prep_castT(const float* __restrict__ Wd1, const float* __restrict__ Wd2,
                           const float* __restrict__ Ws1,
                           u16* __restrict__ o1, u16* __restrict__ o2, u16* __restrict__ o3) {
  int b = blockIdx.x;           // 3*1024 blocks
  int w = b >> 10, rem = b & 1023;
  int tk = rem >> 5, tn = rem & 31;
  const float* src = (w == 0) ? Wd1 : ((w == 1) ? Wd2 : Ws1);
  u16* dst = (w == 0) ? o1 : ((w == 1) ? o2 : o3);
  __shared__ u16 tile[32][33];
  int x = threadIdx.x & 31, y = threadIdx.x >> 5;   // y in 0..7
  int k0 = tk * 32, n0 = tn * 32;
  for (int yy = 0; yy < 32; yy += 8)
    tile[y + yy][x] = f2bu(src[(size_t)(k0 + y + yy) * HD + n0 + x]);
  __syncthreads();
  for (int yy = 0; yy < 32; yy += 8)
    dst[(size_t)(n0 + y + yy) * HD + k0 + x] = tile[x][y + yy];
}

// ---- prep: S0/S1/S2 = column sums of W_s1's feat rows (len/start/end, 16 each), exact fp32 ----
__global__ void prep_svec(const float* __restrict__ Ws1,
                          float* __restrict__ S0, float* __restrict__ S1v, float* __restrict__ S2v) {
  int c = blockIdx.x * 256 + threadIdx.x;
  if (c >= HD) return;
  float a = 0.f, b = 0.f, d = 0.f;
  for (int r = 0; r < 16; ++r) {
    a += Ws1[(size_t)(1024 + r) * HD + c];
    b += Ws1[(size_t)(1040 + r) * HD + c];
    d += Ws1[(size_t)(1056 + r) * HD + c];
  }
  S0[c] = a; S1v[c] = b; S2v[c] = d;
}

// ---- Qp = [0; cumsum(Y, rows)] fp32, per-column parallel scan ----
__global__ void yscan(const float* __restrict__ Y, float* __restrict__ Qp) {
  __shared__ float buf[NTOK];
  int c = blockIdx.x;           // 0..1023
  int t = threadIdx.x;          // 0..383
  buf[t] = Y[(size_t)t * HD + c];
  __syncthreads();
  #pragma unroll
  for (int off = 1; off < NTOK; off <<= 1) {
    float add = (t >= off) ? buf[t - off] : 0.f;
    __syncthreads();
    buf[t] += add;
    __syncthreads();
  }
  if (t == 0) Qp[c] = 0.f;
  Qp[(size_t)(t + 1) * HD + c] = buf[t];
}

// ---- expand: h1[s] = relu((Qp[e]-Qp[i])*inv + b1) -> bf16 [MPAD][1024] ----
// Replaces the 1.6e11-FLOP GEMM1: matmul is linear in the span mean, so
// mean@W1 = (prefix(Y)[e]-prefix(Y)[i])*inv with Y = emb@W1 (tiny GEMM).
__global__ void expand(const float* __restrict__ Qp, const int* __restrict__ spI,
                       const int* __restrict__ spE, const float* __restrict__ spInv,
                       const float* __restrict__ b1, u16* __restrict__ out) {
  int gid = blockIdx.x * 256 + threadIdx.x;   // MPAD*128 threads
  int row = gid >> 7;
  int c0 = (gid & 127) << 3;
  int i = spI[row], e = spE[row];
  float inv = spInv[row];
  const float* pe = Qp + (size_t)e * HD + c0;
  const float* pi = Qp + (size_t)i * HD + c0;
  const float* bb = b1 + c0;
  u16 tmp[8];
  #pragma unroll
  for (int u = 0; u < 8; ++u) {
    float v = (pe[u] - pi[u]) * inv + bb[u];
    v = v > 0.f ? v : 0.f;
    tmp[u] = f2bu(v);
  }
  *(uint4*)(out + (size_t)row * HD + c0) = *(const uint4*)tmp;
}

// ---- GEMM: C[M,1024] = A[M,1024] @ B^T[1024,1024]^T (+ bias, relu)
// R7 structure: 128x128 tile, 4 waves of 64x64, 16x16x32 MFMA, BK=32,
// 0-conflict stripe layout (2 rows per 128-B stripe), ping-pong + vmcnt(4).
// EPI==0: relu+bias, store bf16 C.
// EPI==1: + feats affine, relu, dot W_s2, atomicAdd scores.
// EPI==2: plain fp32 store (no bias/relu), simple block mapping (small Y-GEMM).
template <int EPI>
__global__ __launch_bounds__(256, 3) void gemm_bt(
    const u16* __restrict__ A, const u16* __restrict__ Bt,
    const float* __restrict__ bias, u16* __restrict__ C, float* __restrict__ Cf,
    const int* __restrict__ spI, const int* __restrict__ spE,
    const float* __restrict__ S0, const float* __restrict__ S1v, const float* __restrict__ S2v,
    const float* __restrict__ Ws2, float* __restrict__ scores) {
  __shared__ u16 As[2][128 * BK];   // 8 KB per buffer; [stripe(64)][128B]
  __shared__ u16 Bs[2][128 * BK];
  int bx = blockIdx.x;
  int mt, nt;
  if (EPI == 2) {
    nt = bx & 7; mt = bx >> 3;      // tiny GEMM: plain mapping
  } else {
    int xcd = bx & 7, k = bx >> 3;
    nt = k & 7;
    mt = xcd + 8 * (k >> 3);        // mt%8 == xcd; blocks per XCD share mt (A L2 reuse)
  }
  int m0 = mt * 128, n0 = nt * 128;
  int t = threadIdx.x, lane = t & 63, wid = t >> 6;
  int wm = wid >> 1, wn = wid & 1;
  int q = lane >> 4, r = lane & 15;

  floatx4 acc[4][4] = {};

  // ---- staging geometry (stripe s holds rows 2s,2s+1; sub=(row&1)*4+koct at
  // octet sub^(s&7); one DMA op = 16 rows x 64B, swizzle invariant under +64 rows) ----
  int dsub = (lane & 7) ^ ((lane >> 3) & 7);
  int row0 = wid * 16 + 2 * (lane >> 3) + (dsub >> 2);
  int voff = row0 * HD + (dsub & 3) * 8;          // u16 elems; kt-invariant
  const u16* gA0 = A  + (size_t)m0 * HD;
  const u16* gB0 = Bt + (size_t)n0 * HD;
  int ldsOff0 = wid * 512;                        // u16; wave-uniform dests
  int ldsOff1 = 2048 + wid * 512;                 // +64 rows = +32 stripes

  auto stage = [&](int kt, int b) {
    const u16* pa = gA0 + voff + kt * BK;
    const u16* pb = gB0 + voff + kt * BK;
    gld_lds16(pa,                   &As[b][ldsOff0]);
    gld_lds16(pa + (size_t)64 * HD, &As[b][ldsOff1]);
    gld_lds16(pb,                   &Bs[b][ldsOff0]);
    gld_lds16(pb + (size_t)64 * HD, &Bs[b][ldsOff1]);
  };

  // ---- fragment read offsets (u16 elements) ----
  int oct = (((r & 1) << 2) + q) ^ ((r >> 1) & 7);
  int aoff[4], boff[4];
  #pragma unroll
  for (int x = 0; x < 4; ++x) {
    aoff[x] = (wm * 32 + x * 8 + (r >> 1)) * 64 + oct * 8;
    boff[x] = (wn * 32 + x * 8 + (r >> 1)) * 64 + oct * 8;
  }

  auto compute = [&](int b) {
    short8 af[4];
    #pragma unroll
    for (int x = 0; x < 4; ++x) af[x] = *(const short8*)(&As[b][aoff[x]]);
    #pragma unroll
    for (int ni = 0; ni < 4; ++ni) {
      short8 bf = *(const short8*)(&Bs[b][boff[ni]]);
      #pragma unroll
      for (int mi = 0; mi < 4; ++mi)
        acc[mi][ni] = __builtin_amdgcn_mfma_f32_16x16x32_bf16(af[mi], bf, acc[mi][ni], 0, 0, 0);
    }
  };

  stage(0, 0);
  #pragma unroll 1
  for (int kt = 0; kt < KTS; ++kt) {
    int cur = kt & 1;
    if (kt < KTS - 1) {
      stage(kt + 1, cur ^ 1);
      __builtin_amdgcn_s_waitcnt(VMCNT_IMM(4));   // kt's 4 stage ops done; kt+1's in flight
    } else {
      __builtin_amdgcn_s_waitcnt(VMCNT_IMM(0));
    }
    __builtin_amdgcn_s_barrier();
    compute(cur);
    __builtin_amdgcn_s_barrier();                 // all waves done reading buf cur
  }

  if (EPI == 2) {
    #pragma unroll
    for (int mi = 0; mi < 4; ++mi) {
      int rowb = m0 + wm * 64 + mi * 16 + q * 4;
      #pragma unroll
      for (int ni = 0; ni < 4; ++ni) {
        int col = n0 + wn * 64 + ni * 16 + r;
        #pragma unroll
        for (int e = 0; e < 4; ++e)
          Cf[(size_t)(rowb + e) * HD + col] = acc[mi][ni][e];
      }
    }
  } else if (EPI == 0) {
    #pragma unroll
    for (int mi = 0; mi < 4; ++mi) {
      int rowb = m0 + wm * 64 + mi * 16 + q * 4;
      #pragma unroll
      for (int ni = 0; ni < 4; ++ni) {
        int col = n0 + wn * 64 + ni * 16 + r;
        float bcol = bias[col];
        #pragma unroll
        for (int e = 0; e < 4; ++e) {
          float v = acc[mi][ni][e] + bcol;
          v = v > 0.f ? v : 0.f;
          C[(size_t)(rowb + e) * HD + col] = f2bu(v);
        }
      }
    }
  } else {
    float bcol[4], s0c[4], s1c[4], s2c[4], wsc[4];
    #pragma unroll
    for (int ni = 0; ni < 4; ++ni) {
      int col = n0 + wn * 64 + ni * 16 + r;
      bcol[ni] = bias[col]; s0c[ni] = S0[col]; s1c[ni] = S1v[col];
      s2c[ni] = S2v[col];  wsc[ni] = Ws2[col];
    }
    #pragma unroll
    for (int mi = 0; mi < 4; ++mi) {
      int rowb = m0 + wm * 64 + mi * 16 + q * 4;
      #pragma unroll
      for (int e = 0; e < 4; ++e) {
        int row = rowb + e;
        float fi = (float)spI[row];
        float fe = (float)spE[row];
        float fl = fe - fi;
        float p = 0.f;
        #pragma unroll
        for (int ni = 0; ni < 4; ++ni) {
          float v = acc[mi][ni][e] + bcol[ni] + fl * s0c[ni] + fi * s1c[ni] + fe * s2c[ni];
          v = v > 0.f ? v : 0.f;
          p += v * wsc[ni];
        }
        p += __shfl_xor(p, 1);
        p += __shfl_xor(p, 2);
        p += __shfl_xor(p, 4);
        p += __shfl_xor(p, 8);
        if (r == 0 && row < SPANS) atomicAdd(&scores[row], p);
      }
    }
  }
}

extern "C" void kernel_launch(void* const* d_in, const int* in_sizes, int n_in,
                              void* d_out, int out_size, void* d_ws, size_t ws_size,
                              hipStream_t stream) {
  const int*   sent = (const int*)d_in[0];
  const int*   pos  = (const int*)d_in[1];
  const float* Wwrd = (const float*)d_in[2];
  const float* Wpos = (const float*)d_in[3];
  const float* Wd1  = (const float*)d_in[4];
  const float* bd1  = (const float*)d_in[5];
  const float* Wd2  = (const float*)d_in[6];
  const float* bd2  = (const float*)d_in[7];
  const float* Ws1  = (const float*)d_in[8];
  const float* bs1  = (const float*)d_in[9];
  const float* Ws2  = (const float*)d_in[10];
  const float* bs2  = (const float*)d_in[11];
  float* scores = (float*)d_out;

  char* w = (char*)d_ws;
  size_t o = 0;
  auto alloc = [&](size_t bytes) {
    char* p = w + o;
    o = (o + bytes + 255) & ~(size_t)255;
    return p;
  };
  int*   spI   = (int*)  alloc((size_t)MPAD * 4);
  int*   spE   = (int*)  alloc((size_t)MPAD * 4);
  float* spInv = (float*)alloc((size_t)MPAD * 4);
  float* S0    = (float*)alloc(4096);
  float* S1v   = (float*)alloc(4096);
  float* S2v   = (float*)alloc(4096);
  u16*   embB  = (u16*)  alloc((size_t)NTOK * HD * 2);
  float* Ybuf  = (float*)alloc((size_t)NTOK * HD * 4);
  float* Qp    = (float*)alloc((size_t)(NTOK + 1) * HD * 4);
  u16* Wd1t = (u16*)alloc((size_t)HD * HD * 2);
  u16* Wd2t = (u16*)alloc((size_t)HD * HD * 2);
  u16* Ws1t = (u16*)alloc((size_t)HD * HD * 2);
  u16* bufA = (u16*)alloc((size_t)MPAD * HD * 2);
  u16* bufB = (u16*)alloc((size_t)MPAD * HD * 2);

  emb_gather<<<NTOK, 256, 0, stream>>>(sent, pos, Wwrd, Wpos, embB);
  prep_spans<<<(MPAD + 255) / 256, 256, 0, stream>>>(spI, spE, spInv, scores, bs2);
  prep_castT<<<3 * 1024, 256, 0, stream>>>(Wd1, Wd2, Ws1, Wd1t, Wd2t, Ws1t);
  prep_svec <<<4, 256, 0, stream>>>(Ws1, S0, S1v, S2v);

  // Y = emb @ Wd1  (384x1024x1024, 24 blocks, fp32 out)
  gemm_bt<2><<<(NTOK / 128) * 8, 256, 0, stream>>>(embB, Wd1t, nullptr, nullptr, Ybuf,
                                                   nullptr, nullptr, nullptr, nullptr, nullptr,
                                                   nullptr, nullptr);
  yscan<<<HD, NTOK, 0, stream>>>(Ybuf, Qp);
  expand<<<MPAD / 2, 256, 0, stream>>>(Qp, spI, spE, spInv, bd1, bufA);

  gemm_bt<0><<<MTILES * 8, 256, 0, stream>>>(bufA, Wd2t, bd2, bufB, nullptr,
                                             nullptr, nullptr, nullptr, nullptr, nullptr,
                                             nullptr, nullptr);
  gemm_bt<1><<<MTILES * 8, 256, 0, stream>>>(bufB, Ws1t, bs1, nullptr, nullptr,
                                             spI, spE, S0, S1v, S2v, Ws2, scores);
}